// Round 5
// baseline (231.813 us; speedup 1.0000x reference)
//
#include <hip/hip_runtime.h>

// INT8 LSTM cell v5: i8 GEMM, A-in-registers + W double-buffered in LDS.
//   gates = A @ W^T + b,  A = [x|h] (16384 x 1024), W = [w_ih|w_hh] (2048 x 1024)
// W is EXACTLY int8*scale (reference quant_dequant) -> recovered losslessly.
// A quantized per-row. mfma_i32_16x16x64_i8, BK=128 int8, KSTEPS=8.
// v5 structure: A-tiles have ZERO cross-wave reuse -> load A fragments directly
// global->VGPR from a fragment-ordered ws layout (8 coalesced dwordx4/wave/ks).
// Only W (shared by all 4 waves) goes through LDS, double-buffered (2x16KB),
// ONE barrier per ks; W(ks+1)+A(ks+1) issued before compute(ks) so the barrier
// drain overlaps 64 MFMAs. Epilogue: in-register dequant + LSTM math.

typedef __attribute__((ext_vector_type(4))) int int4v;
typedef __attribute__((ext_vector_type(8))) short short8;
typedef __attribute__((ext_vector_type(4))) float f32x4;
typedef unsigned int u32;
typedef unsigned short u16;
typedef unsigned char u8;

#define BATCH 16384
#define HID 512
#define KTOT 1024
#define BM 256
#define KSTEPS 8                  // KTOT / 128
#define TILEA_BYTES 32768         // 256 rows * 128 int8 (fragment-ordered)
#define TILEW_BYTES 16384         // 128 rows * 128 int8 (swizzled for LDS)
#define NBM 64
#define NBN 16
#define WSA_BYTES ((size_t)NBM * KSTEPS * TILEA_BYTES)   // 16 MB
#define WSW_BYTES ((size_t)NBN * KSTEPS * TILEW_BYTES)   // 2 MB
#define SCALE_OFF (WSA_BYTES + WSW_BYTES)                // per-row A scales (64 KB)
#define PART_OFF (SCALE_OFF + 65536)                     // 512 W-max partials
#define SW_OFF (PART_OFF + 2048)                         // W scale scalar
#define WS_NEEDED (SW_OFF + 64)

__device__ __forceinline__ float sigmoidf_(float v) { return 1.0f / (1.0f + __expf(-v)); }
__device__ __forceinline__ float tanhf_(float v) { return 1.0f - 2.0f / (__expf(2.0f * v) + 1.0f); }

__device__ __forceinline__ void gload_lds16(const void* g, void* l) {
    __builtin_amdgcn_global_load_lds(
        (const __attribute__((address_space(1))) u32*)g,
        (__attribute__((address_space(3))) u32*)l, 16, 0, 0);
}

__device__ __forceinline__ u32 pack4(float a, float b, float c, float d, float inv) {
    int q0 = (int)rintf(a * inv), q1 = (int)rintf(b * inv);
    int q2 = (int)rintf(c * inv), q3 = (int)rintf(d * inv);
    return (q0 & 255) | ((q1 & 255) << 8) | ((q2 & 255) << 16) | ((q3 & 255) << 24);
}

// ---- Stage 0: per-block partial max|W| (512 partials) ----
__global__ __launch_bounds__(256) void wmax_part(
    const float* __restrict__ w_ih, const float* __restrict__ w_hh, float* __restrict__ part)
{
    const u32 b = blockIdx.x;
    const float* src = (b < 256) ? (w_ih + (size_t)b * 4096) : (w_hh + (size_t)(b - 256) * 4096);
    const u32 t = threadIdx.x;
    float am = 0.f;
    const float4* p = (const float4*)src + t;
    #pragma unroll
    for (int j = 0; j < 4; ++j) {
        float4 v = p[j * 256];
        am = fmaxf(am, fmaxf(fmaxf(fabsf(v.x), fabsf(v.y)), fmaxf(fabsf(v.z), fabsf(v.w))));
    }
    #pragma unroll
    for (int o = 32; o >= 1; o >>= 1) am = fmaxf(am, __shfl_xor(am, o, 64));
    __shared__ float red[4];
    if ((t & 63) == 0) red[t >> 6] = am;
    __syncthreads();
    if (t == 0) part[b] = fmaxf(fmaxf(red[0], red[1]), fmaxf(red[2], red[3]));
}

// ---- Stage 1b: pack W -> exact int8 swizzled LDS-tiles (unchanged layout). ----
// chunk index = ((bn*8+ks)*128 + row)*8 + cphys, cphys = clog ^ (row&7).
__global__ __launch_bounds__(256) void pack_w(
    const float* __restrict__ w_ih, const float* __restrict__ w_hh,
    const float* __restrict__ part, u8* __restrict__ wsW, float* __restrict__ swOut)
{
    const u32 t = threadIdx.x;
    float am = fmaxf(part[t], part[t + 256]);
    #pragma unroll
    for (int o = 32; o >= 1; o >>= 1) am = fmaxf(am, __shfl_xor(am, o, 64));
    __shared__ float red[4];
    if ((t & 63) == 0) red[t >> 6] = am;
    __syncthreads();
    const float wmax = fmaxf(fmaxf(red[0], red[1]), fmaxf(red[2], red[3]));
    const float inv = 127.0f / wmax;
    if (blockIdx.x == 0 && t == 0) *swOut = wmax * (1.0f / 127.0f);

    const u32 widx = blockIdx.x * 256 + t;
    const u32 cphys = widx & 7;
    const u32 row = (widx >> 3) & 127;
    const u32 ks = (widx >> 10) & 7;
    const u32 bn = widx >> 13;
    const u32 clog = cphys ^ (row & 7);
    const u32 g = row >> 5, rr = row & 31;
    const u32 wrow = g * 512 + bn * 32 + rr;
    const u32 kglob = ks * 128 + clog * 16;
    const float* src = (kglob < 512) ? (w_ih + (size_t)wrow * 512 + kglob)
                                     : (w_hh + (size_t)wrow * 512 + (kglob - 512));
    u32 wds[4];
    #pragma unroll
    for (int j = 0; j < 4; ++j) {
        float4 v = *((const float4*)src + j);
        wds[j] = pack4(v.x, v.y, v.z, v.w, inv);
    }
    int4v val = {(int)wds[0], (int)wds[1], (int)wds[2], (int)wds[3]};
    *(int4v*)(wsW + (size_t)widx * 16) = val;
}

// ---- Stage 1a: pack A, FRAGMENT-ORDERED for direct register loads. ----
// Layout: ((((bm*8+ks)*4+wv)*8 + c)*1024 + (quad*16+colin)*16, c = rf*2+ks2.
// GEMM lane L=quad*16+colin of wave wv reads chunk c as one coalesced dwordx4.
__global__ __launch_bounds__(256) void pack_a(
    const float* __restrict__ x, const float* __restrict__ h_prev,
    u8* __restrict__ wsA, float* __restrict__ aScale)
{
    const u32 t = threadIdx.x;
    const u32 lane = t & 63;
    const u32 m = blockIdx.x * 4 + (t >> 6);
    const u32 k0 = lane * 16;                 // lane covers global k [16*lane, +16)
    const float* src = (k0 < 512) ? (x + (size_t)m * 512 + k0)
                                  : (h_prev + (size_t)m * 512 + (k0 - 512));
    float4 v[4];
    #pragma unroll
    for (int j = 0; j < 4; ++j) v[j] = *((const float4*)src + j);
    float am = 0.f;
    #pragma unroll
    for (int j = 0; j < 4; ++j)
        am = fmaxf(am, fmaxf(fmaxf(fabsf(v[j].x), fabsf(v[j].y)),
                             fmaxf(fabsf(v[j].z), fabsf(v[j].w))));
    #pragma unroll
    for (int o = 32; o >= 1; o >>= 1) am = fmaxf(am, __shfl_xor(am, o, 64));
    const float inv = (am > 0.f) ? 127.0f / am : 0.f;
    if (lane == 0) aScale[m] = am * (1.0f / 127.0f);
    u32 wds[4];
    #pragma unroll
    for (int j = 0; j < 4; ++j) wds[j] = pack4(v[j].x, v[j].y, v[j].z, v[j].w, inv);

    const u32 bm = m >> 8;
    const u32 row = m & 255;
    const u32 wv = row >> 6;
    const u32 rf = (row >> 4) & 3;
    const u32 colin = row & 15;
    const u32 ks = lane >> 3;
    const u32 cit = lane & 7;                 // k-chunk within tile
    const u32 ks2 = cit >> 2, quad = cit & 3;
    const u32 c = rf * 2 + ks2;
    int4v val = {(int)wds[0], (int)wds[1], (int)wds[2], (int)wds[3]};
    *(int4v*)(wsA + ((((size_t)bm * 8 + ks) * 4 + wv) * 8 + c) * 1024
                    + (quad * 16 + colin) * 16) = val;
}

// ---- Stage 2: i8 GEMM, A in regs, W dbuf LDS, 1 barrier/ks + LSTM epilogue. ----
__global__ __launch_bounds__(256, 2) void lstm_gemm(
    const u8* __restrict__ wsA, const u8* __restrict__ wsW,
    const float* __restrict__ aScale, const float* __restrict__ swPtr,
    const float* __restrict__ c_prev,
    const float* __restrict__ b_ih, const float* __restrict__ b_hh,
    float* __restrict__ h_out, float* __restrict__ c_out)
{
    __shared__ u8 sW[2][TILEW_BYTES];  // 32 KB double buffer

    const int t = threadIdx.x;
    const int bn = blockIdx.x & 15;
    const int bm = blockIdx.x >> 4;   // consecutive bids share the A panel (L2)
    const int n0 = bn * 32;
    const int rowBase = bm * BM;

    const int lane = t & 63;
    const int wv = t >> 6;
    const int colin = lane & 15;
    const int quad = lane >> 4;
    const int stageOff = t * 16;

    int4v acc[4][2][4];
    #pragma unroll
    for (int rf = 0; rf < 4; ++rf)
        #pragma unroll
        for (int cc = 0; cc < 2; ++cc)
            #pragma unroll
            for (int g = 0; g < 4; ++g)
                acc[rf][cc][g] = (int4v){0, 0, 0, 0};

    const char* gA = (const char*)wsA + (size_t)bm * (KSTEPS * TILEA_BYTES)
                     + wv * 8192 + lane * 16;
    const char* gW = (const char*)wsW + (size_t)bn * (KSTEPS * TILEW_BYTES);

    int4v areg[2][8];
    // Prologue: A(0) -> regs, W(0) -> sW[0]
    #pragma unroll
    for (int c = 0; c < 8; ++c)
        areg[0][c] = *(const int4v*)(gA + c * 1024);
    #pragma unroll
    for (int j = 0; j < 4; ++j)
        gload_lds16(gW + j * 4096 + stageOff, &sW[0][0] + j * 4096 + stageOff);
    __syncthreads();

    #pragma unroll
    for (int ks = 0; ks < KSTEPS; ++ks) {
        const int cur = ks & 1, nxt = cur ^ 1;
        if (ks < KSTEPS - 1) {
            // prefetch W(ks+1) -> other LDS buffer, A(ks+1) -> other reg set;
            // stays in flight across compute; drained by the single barrier below
            #pragma unroll
            for (int j = 0; j < 4; ++j)
                gload_lds16(gW + (size_t)(ks + 1) * TILEW_BYTES + j * 4096 + stageOff,
                            &sW[nxt][0] + j * 4096 + stageOff);
            #pragma unroll
            for (int c = 0; c < 8; ++c)
                areg[nxt][c] = *(const int4v*)(gA + (size_t)(ks + 1) * TILEA_BYTES + c * 1024);
        }
        #pragma unroll
        for (int ks2 = 0; ks2 < 2; ++ks2) {
            int4v bfr[2][4];
            #pragma unroll
            for (int cc = 0; cc < 2; ++cc)
                #pragma unroll
                for (int g = 0; g < 4; ++g) {
                    const int wrow = g * 32 + cc * 16 + colin;
                    const int boff = wrow * 128 + (((ks2 * 4 + quad) ^ (wrow & 7)) * 16);
                    bfr[cc][g] = *(const int4v*)(&sW[cur][0] + boff);
                }
            #pragma unroll
            for (int rf = 0; rf < 4; ++rf)
                #pragma unroll
                for (int cc = 0; cc < 2; ++cc)
                    #pragma unroll
                    for (int g = 0; g < 4; ++g)
                        acc[rf][cc][g] = __builtin_amdgcn_mfma_i32_16x16x64_i8(
                            areg[cur][rf * 2 + ks2], bfr[cc][g], acc[rf][cc][g], 0, 0, 0);
        }
        if (ks < KSTEPS - 1) __syncthreads();
    }

    // Epilogue: dequant + bias + LSTM math, all in-lane.
    const float sw = *swPtr;
    float rsc[4][4];
    #pragma unroll
    for (int rf = 0; rf < 4; ++rf)
        #pragma unroll
        for (int reg = 0; reg < 4; ++reg)
            rsc[rf][reg] = aScale[rowBase + wv * 64 + rf * 16 + quad * 4 + reg] * sw;

    float bsum[2][4];
    #pragma unroll
    for (int cc = 0; cc < 2; ++cc) {
        const int colg = n0 + cc * 16 + colin;
        #pragma unroll
        for (int g = 0; g < 4; ++g)
            bsum[cc][g] = b_ih[g * 512 + colg] + b_hh[g * 512 + colg];
    }

    #pragma unroll
    for (int rf = 0; rf < 4; ++rf)
        #pragma unroll
        for (int cc = 0; cc < 2; ++cc) {
            const int colg = n0 + cc * 16 + colin;
            #pragma unroll
            for (int reg = 0; reg < 4; ++reg) {
                const int row = rowBase + wv * 64 + rf * 16 + quad * 4 + reg;
                const size_t off = (size_t)row * 512 + colg;
                const float s = rsc[rf][reg];
                const float ig = (float)acc[rf][cc][0][reg] * s + bsum[cc][0];
                const float fg = (float)acc[rf][cc][1][reg] * s + bsum[cc][1];
                const float gg = (float)acc[rf][cc][2][reg] * s + bsum[cc][2];
                const float og = (float)acc[rf][cc][3][reg] * s + bsum[cc][3];
                const float cp = __builtin_nontemporal_load(c_prev + off);
                const float cn = sigmoidf_(fg) * cp + sigmoidf_(ig) * tanhf_(gg);
                const float hn = sigmoidf_(og) * tanhf_(cn);
                __builtin_nontemporal_store(hn, h_out + off);
                __builtin_nontemporal_store(cn, c_out + off);
            }
        }
}

// ---- Fallback (round-1 kernel, proven): used only if ws_size < WS_NEEDED ----
#define LDSK 72
__device__ __forceinline__ u16 f2bf(float f) {
    u32 u = __builtin_bit_cast(u32, f);
    u += 0x7FFFu + ((u >> 16) & 1u);
    return (u16)(u >> 16);
}
__global__ __launch_bounds__(256, 3) void lstm_fused_v1(
    const float* __restrict__ x, const float* __restrict__ h_prev,
    const float* __restrict__ c_prev, const float* __restrict__ w_ih,
    const float* __restrict__ w_hh, const float* __restrict__ b_ih,
    const float* __restrict__ b_hh, float* __restrict__ h_out,
    float* __restrict__ c_out)
{
    __shared__ u16 sA[128][LDSK];
    __shared__ u16 sW[128][LDSK];
    const int t = threadIdx.x;
    const int bn = blockIdx.x & 15, bm = blockIdx.x >> 4;
    const int n0 = bn * 32, rowBase = bm * 128;
    const int srow = t >> 4, scol = t & 15;
    const int lane = t & 63, wv = t >> 6, colin = lane & 15, quad = lane >> 4;
    f32x4 acc[2][2][4];
    #pragma unroll
    for (int rf = 0; rf < 2; ++rf)
        #pragma unroll
        for (int cc = 0; cc < 2; ++cc)
            #pragma unroll
            for (int g = 0; g < 4; ++g) acc[rf][cc][g] = (f32x4){0.f, 0.f, 0.f, 0.f};
    for (int k0 = 0; k0 < KTOT; k0 += 64) {
        const int kk = (k0 < 512) ? k0 : (k0 - 512);
        const float* aSrc = (k0 < 512) ? x : h_prev;
        const float* wSrc = (k0 < 512) ? w_ih : w_hh;
        __syncthreads();
        #pragma unroll
        for (int p = 0; p < 8; ++p) {
            const int r = srow + p * 16;
            const float4 av = *(const float4*)(aSrc + (size_t)(rowBase + r) * 512 + kk + scol * 4);
            ushort4 ap; ap.x = f2bf(av.x); ap.y = f2bf(av.y); ap.z = f2bf(av.z); ap.w = f2bf(av.w);
            *(ushort4*)&sA[r][scol * 4] = ap;
            const int gate = r >> 5, rr = r & 31;
            const float4 wvv = *(const float4*)(wSrc + (size_t)(gate * 512 + n0 + rr) * 512 + kk + scol * 4);
            ushort4 wp; wp.x = f2bf(wvv.x); wp.y = f2bf(wvv.y); wp.z = f2bf(wvv.z); wp.w = f2bf(wvv.w);
            *(ushort4*)&sW[r][scol * 4] = wp;
        }
        __syncthreads();
        #pragma unroll
        for (int ks = 0; ks < 2; ++ks) {
            short8 af[2];
            #pragma unroll
            for (int rf = 0; rf < 2; ++rf)
                af[rf] = *(const short8*)&sA[wv * 32 + rf * 16 + colin][ks * 32 + quad * 8];
            short8 bfr[2][4];
            #pragma unroll
            for (int cc = 0; cc < 2; ++cc)
                #pragma unroll
                for (int g = 0; g < 4; ++g)
                    bfr[cc][g] = *(const short8*)&sW[g * 32 + cc * 16 + colin][ks * 32 + quad * 8];
            #pragma unroll
            for (int rf = 0; rf < 2; ++rf)
                #pragma unroll
                for (int cc = 0; cc < 2; ++cc)
                    #pragma unroll
                    for (int g = 0; g < 4; ++g)
                        acc[rf][cc][g] = __builtin_amdgcn_mfma_f32_16x16x32_bf16(
                            af[rf], bfr[cc][g], acc[rf][cc][g], 0, 0, 0);
        }
    }
    float bsum[2][4];
    #pragma unroll
    for (int cc = 0; cc < 2; ++cc) {
        const int colg = n0 + cc * 16 + colin;
        #pragma unroll
        for (int g = 0; g < 4; ++g) bsum[cc][g] = b_ih[g * 512 + colg] + b_hh[g * 512 + colg];
    }
    #pragma unroll
    for (int rf = 0; rf < 2; ++rf)
        #pragma unroll
        for (int cc = 0; cc < 2; ++cc) {
            const int colg = n0 + cc * 16 + colin;
            #pragma unroll
            for (int reg = 0; reg < 4; ++reg) {
                const int row = rowBase + wv * 32 + rf * 16 + quad * 4 + reg;
                const size_t off = (size_t)row * 512 + colg;
                const float ig = acc[rf][cc][0][reg] + bsum[cc][0];
                const float fg = acc[rf][cc][1][reg] + bsum[cc][1];
                const float gg = acc[rf][cc][2][reg] + bsum[cc][2];
                const float og = acc[rf][cc][3][reg] + bsum[cc][3];
                const float cp = c_prev[off];
                const float cn = sigmoidf_(fg) * cp + sigmoidf_(ig) * tanhf_(gg);
                const float hn = sigmoidf_(og) * tanhf_(cn);
                h_out[off] = hn;
                c_out[off] = cn;
            }
        }
}

extern "C" void kernel_launch(void* const* d_in, const int* in_sizes, int n_in,
                              void* d_out, int out_size, void* d_ws, size_t ws_size,
                              hipStream_t stream) {
    const float* x      = (const float*)d_in[0];
    const float* h_prev = (const float*)d_in[1];
    const float* c_prev = (const float*)d_in[2];
    const float* w_ih   = (const float*)d_in[3];
    const float* w_hh   = (const float*)d_in[4];
    const float* b_ih   = (const float*)d_in[5];
    const float* b_hh   = (const float*)d_in[6];
    float* h_out = (float*)d_out;
    float* c_out = h_out + (size_t)BATCH * HID;

    if (ws_size >= WS_NEEDED) {
        u8* wsA = (u8*)d_ws;
        u8* wsW = (u8*)d_ws + WSA_BYTES;
        float* aScale = (float*)((char*)d_ws + SCALE_OFF);
        float* part   = (float*)((char*)d_ws + PART_OFF);
        float* swOut  = (float*)((char*)d_ws + SW_OFF);
        wmax_part<<<512, 256, 0, stream>>>(w_ih, w_hh, part);
        pack_w<<<512, 256, 0, stream>>>(w_ih, w_hh, part, wsW, swOut);
        pack_a<<<BATCH / 4, 256, 0, stream>>>(x, h_prev, wsA, aScale);
        lstm_gemm<<<NBM * NBN, 256, 0, stream>>>(wsA, wsW, aScale, swOut, c_prev,
                                                 b_ih, b_hh, h_out, c_out);
    } else {
        lstm_fused_v1<<<128 * 16, 256, 0, stream>>>(x, h_prev, c_prev, w_ih, w_hh,
                                                    b_ih, b_hh, h_out, c_out);
    }
}

// Round 6
// 209.722 us; speedup vs baseline: 1.1053x; 1.1053x over previous
//
#include <hip/hip_runtime.h>

// INT8 LSTM cell v6: round-4 i8 GEMM structure (proven 72.6us) + XCD-aware
// block swizzle so the 16 bn-sibling blocks sharing one A panel land on the
// SAME XCD (bid%8 round-robin dispatch assumption -> L2-local A staging).
//   gates = A @ W^T + b,  A=[x|h] (16384x1024), W=[w_ih|w_hh] (2048x1024)
// W is EXACTLY int8*scale (reference quant_dequant) -> recovered losslessly
// with the global scale. A quantized per-row. mfma_i32_16x16x64_i8, BK=128.
// v5 (A-in-reg + 1-barrier dbuf) REGRESSED (84.6us): compiler drains manual
// prefetch at the barrier (m131-m141 pattern). Keep the 2-barrier m97 shape.

typedef __attribute__((ext_vector_type(4))) int int4v;
typedef __attribute__((ext_vector_type(8))) short short8;
typedef __attribute__((ext_vector_type(4))) float f32x4;
typedef unsigned int u32;
typedef unsigned short u16;
typedef unsigned char u8;

#define BATCH 16384
#define HID 512
#define KTOT 1024
#define BM 256
#define KSTEPS 8                  // KTOT / 128
#define TILEA_BYTES 32768         // 256 rows * 128 int8 (swizzled)
#define TILEW_BYTES 16384         // 128 rows * 128 int8 (swizzled)
#define NBM 64
#define NBN 16
#define WSA_BYTES ((size_t)NBM * KSTEPS * TILEA_BYTES)   // 16 MB
#define WSW_BYTES ((size_t)NBN * KSTEPS * TILEW_BYTES)   // 2 MB
#define SCALE_OFF (WSA_BYTES + WSW_BYTES)                // per-row A scales (64 KB)
#define PART_OFF (SCALE_OFF + 65536)                     // 512 W-max partials
#define SW_OFF (PART_OFF + 2048)                         // W scale scalar
#define WS_NEEDED (SW_OFF + 64)
#define PACKA_BLOCKS (BATCH / 4)                         // 4096

__device__ __forceinline__ float sigmoidf_(float v) { return 1.0f / (1.0f + __expf(-v)); }
__device__ __forceinline__ float tanhf_(float v) { return 1.0f - 2.0f / (__expf(2.0f * v) + 1.0f); }

__device__ __forceinline__ void gload_lds16(const void* g, void* l) {
    __builtin_amdgcn_global_load_lds(
        (const __attribute__((address_space(1))) u32*)g,
        (__attribute__((address_space(3))) u32*)l, 16, 0, 0);
}

__device__ __forceinline__ u32 pack4(float a, float b, float c, float d, float inv) {
    int q0 = (int)rintf(a * inv), q1 = (int)rintf(b * inv);
    int q2 = (int)rintf(c * inv), q3 = (int)rintf(d * inv);
    return (q0 & 255) | ((q1 & 255) << 8) | ((q2 & 255) << 16) | ((q3 & 255) << 24);
}

// ---- Stage 1a (fused): pack A into swizzled tiles + W partial-max. ----
// Blocks [0, 4096): pack_a (one wave per A row). Blocks [4096, 4608): wmax.
__global__ __launch_bounds__(256) void pack_a_wmax(
    const float* __restrict__ x, const float* __restrict__ h_prev,
    const float* __restrict__ w_ih, const float* __restrict__ w_hh,
    u8* __restrict__ wsA, float* __restrict__ aScale, float* __restrict__ part)
{
    const u32 t = threadIdx.x;
    if (blockIdx.x >= PACKA_BLOCKS) {
        const u32 b = blockIdx.x - PACKA_BLOCKS;   // 0..511, 4096 floats each
        const float* src = (b < 256) ? (w_ih + (size_t)b * 4096)
                                     : (w_hh + (size_t)(b - 256) * 4096);
        float am = 0.f;
        const float4* p = (const float4*)src + t;
        #pragma unroll
        for (int j = 0; j < 4; ++j) {
            float4 v = p[j * 256];
            am = fmaxf(am, fmaxf(fmaxf(fabsf(v.x), fabsf(v.y)), fmaxf(fabsf(v.z), fabsf(v.w))));
        }
        #pragma unroll
        for (int o = 32; o >= 1; o >>= 1) am = fmaxf(am, __shfl_xor(am, o, 64));
        __shared__ float red[4];
        if ((t & 63) == 0) red[t >> 6] = am;
        __syncthreads();
        if (t == 0) part[b] = fmaxf(fmaxf(red[0], red[1]), fmaxf(red[2], red[3]));
        return;
    }
    const u32 lane = t & 63;
    const u32 m = blockIdx.x * 4 + (t >> 6);
    const u32 k0 = lane * 16;
    const float* src = (k0 < 512) ? (x + (size_t)m * 512 + k0)
                                  : (h_prev + (size_t)m * 512 + (k0 - 512));
    float4 v[4];
    #pragma unroll
    for (int j = 0; j < 4; ++j) v[j] = *((const float4*)src + j);
    float am = 0.f;
    #pragma unroll
    for (int j = 0; j < 4; ++j)
        am = fmaxf(am, fmaxf(fmaxf(fabsf(v[j].x), fabsf(v[j].y)),
                             fmaxf(fabsf(v[j].z), fabsf(v[j].w))));
    #pragma unroll
    for (int o = 32; o >= 1; o >>= 1) am = fmaxf(am, __shfl_xor(am, o, 64));
    const float inv = (am > 0.f) ? 127.0f / am : 0.f;
    if (lane == 0) aScale[m] = am * (1.0f / 127.0f);
    u32 wds[4];
    #pragma unroll
    for (int j = 0; j < 4; ++j) wds[j] = pack4(v[j].x, v[j].y, v[j].z, v[j].w, inv);
    // swizzled LDS-tile layout: chunk = ((bm*8+ks)*256 + row)*8 + cphys
    const u32 bm = m >> 8, row = m & 255;
    const u32 ks = lane >> 3, clog = lane & 7;
    const u32 cphys = clog ^ (row & 7);
    int4v val = {(int)wds[0], (int)wds[1], (int)wds[2], (int)wds[3]};
    *(int4v*)(wsA + ((((size_t)bm * 8 + ks) * 256 + row) * 8 + cphys) * 16) = val;
}

// ---- Stage 1b: pack W -> exact int8 swizzled tiles. ----
// chunk index = ((bn*8+ks)*128 + row)*8 + cphys, cphys = clog ^ (row&7).
__global__ __launch_bounds__(256) void pack_w(
    const float* __restrict__ w_ih, const float* __restrict__ w_hh,
    const float* __restrict__ part, u8* __restrict__ wsW, float* __restrict__ swOut)
{
    const u32 t = threadIdx.x;
    float am = fmaxf(part[t], part[t + 256]);
    #pragma unroll
    for (int o = 32; o >= 1; o >>= 1) am = fmaxf(am, __shfl_xor(am, o, 64));
    __shared__ float red[4];
    if ((t & 63) == 0) red[t >> 6] = am;
    __syncthreads();
    const float wmax = fmaxf(fmaxf(red[0], red[1]), fmaxf(red[2], red[3]));
    const float inv = 127.0f / wmax;   // exact: W = q*s_w, wmax = 127*s_w
    if (blockIdx.x == 0 && t == 0) *swOut = wmax * (1.0f / 127.0f);

    const u32 widx = blockIdx.x * 256 + t;
    const u32 cphys = widx & 7;
    const u32 row = (widx >> 3) & 127;
    const u32 ks = (widx >> 10) & 7;
    const u32 bn = widx >> 13;
    const u32 clog = cphys ^ (row & 7);
    const u32 g = row >> 5, rr = row & 31;
    const u32 wrow = g * 512 + bn * 32 + rr;
    const u32 kglob = ks * 128 + clog * 16;
    const float* src = (kglob < 512) ? (w_ih + (size_t)wrow * 512 + kglob)
                                     : (w_hh + (size_t)wrow * 512 + (kglob - 512));
    u32 wds[4];
    #pragma unroll
    for (int j = 0; j < 4; ++j) {
        float4 v = *((const float4*)src + j);
        wds[j] = pack4(v.x, v.y, v.z, v.w, inv);
    }
    int4v val = {(int)wds[0], (int)wds[1], (int)wds[2], (int)wds[3]};
    *(int4v*)(wsW + (size_t)widx * 16) = val;
}

// ---- Stage 2: i8 GEMM (round-4 structure) + XCD swizzle + LSTM epilogue. ----
__global__ __launch_bounds__(256, 2) void lstm_gemm(
    const u8* __restrict__ wsA, const u8* __restrict__ wsW,
    const float* __restrict__ aScale, const float* __restrict__ swPtr,
    const float* __restrict__ c_prev,
    const float* __restrict__ b_ih, const float* __restrict__ b_hh,
    float* __restrict__ h_out, float* __restrict__ c_out)
{
    __shared__ u8 sA[TILEA_BYTES];  // 32 KB, swizzled, NO padding (global_load_lds)
    __shared__ u8 sW[TILEW_BYTES];  // 16 KB

    const int t = threadIdx.x;
    // XCD-aware swizzle (assumes bid%8 round-robin XCD dispatch): the 16
    // bn-siblings of each bm get bids = slot*8 + xcd with consecutive slots
    // -> same XCD, temporally adjacent -> A panel stays in that XCD's L2.
    // If the mapping assumption is wrong this only affects locality, not
    // correctness (every (bm,bn) still covered exactly once).
    const u32 bid = blockIdx.x;
    const u32 xcd = bid & 7;
    const u32 slot = bid >> 3;               // 0..127
    const int bm = (int)((slot >> 4) * 8 + xcd);   // 8 bm-panels per XCD
    const int bn = (int)(slot & 15);
    const int n0 = bn * 32;
    const int rowBase = bm * BM;

    const int lane = t & 63;
    const int wv = t >> 6;
    const int colin = lane & 15;
    const int quad = lane >> 4;
    const int stageOff = t * 16;

    int4v acc[4][2][4];  // [row-frag][col-frag][gate]
    #pragma unroll
    for (int rf = 0; rf < 4; ++rf)
        #pragma unroll
        for (int cc = 0; cc < 2; ++cc)
            #pragma unroll
            for (int g = 0; g < 4; ++g)
                acc[rf][cc][g] = (int4v){0, 0, 0, 0};

    const char* gA = (const char*)wsA + (size_t)bm * KSTEPS * TILEA_BYTES;
    const char* gW = (const char*)wsW + (size_t)bn * KSTEPS * TILEW_BYTES;

    #pragma unroll 1
    for (int ks = 0; ks < KSTEPS; ++ks) {
        __syncthreads();
        #pragma unroll
        for (int j = 0; j < 8; ++j)
            gload_lds16(gA + (size_t)ks * TILEA_BYTES + j * 4096 + stageOff,
                        (char*)sA + j * 4096 + stageOff);
        #pragma unroll
        for (int j = 0; j < 4; ++j)
            gload_lds16(gW + (size_t)ks * TILEW_BYTES + j * 4096 + stageOff,
                        (char*)sW + j * 4096 + stageOff);
        __syncthreads();

        #pragma unroll
        for (int ks2 = 0; ks2 < 2; ++ks2) {
            int4v af[4];
            #pragma unroll
            for (int rf = 0; rf < 4; ++rf) {
                const int row = wv * 64 + rf * 16 + colin;
                const int boff = row * 128 + (((ks2 * 4 + quad) ^ (row & 7)) * 16);
                af[rf] = *(const int4v*)((const char*)sA + boff);
            }
            int4v bfr[2][4];
            #pragma unroll
            for (int cc = 0; cc < 2; ++cc)
                #pragma unroll
                for (int g = 0; g < 4; ++g) {
                    const int wrow = g * 32 + cc * 16 + colin;
                    const int boff = wrow * 128 + (((ks2 * 4 + quad) ^ (wrow & 7)) * 16);
                    bfr[cc][g] = *(const int4v*)((const char*)sW + boff);
                }
            #pragma unroll
            for (int rf = 0; rf < 4; ++rf)
                #pragma unroll
                for (int cc = 0; cc < 2; ++cc)
                    #pragma unroll
                    for (int g = 0; g < 4; ++g)
                        acc[rf][cc][g] = __builtin_amdgcn_mfma_i32_16x16x64_i8(
                            af[rf], bfr[cc][g], acc[rf][cc][g], 0, 0, 0);
        }
    }

    // Epilogue: dequant (per-row scale * W scale), bias, LSTM math — all in-lane.
    const float sw = *swPtr;
    float rsc[4][4];
    #pragma unroll
    for (int rf = 0; rf < 4; ++rf)
        #pragma unroll
        for (int reg = 0; reg < 4; ++reg)
            rsc[rf][reg] = aScale[rowBase + wv * 64 + rf * 16 + quad * 4 + reg] * sw;

    float bsum[2][4];
    #pragma unroll
    for (int cc = 0; cc < 2; ++cc) {
        const int colg = n0 + cc * 16 + colin;
        #pragma unroll
        for (int g = 0; g < 4; ++g)
            bsum[cc][g] = b_ih[g * 512 + colg] + b_hh[g * 512 + colg];
    }

    #pragma unroll
    for (int rf = 0; rf < 4; ++rf)
        #pragma unroll
        for (int cc = 0; cc < 2; ++cc) {
            const int colg = n0 + cc * 16 + colin;
            #pragma unroll
            for (int reg = 0; reg < 4; ++reg) {
                const int row = rowBase + wv * 64 + rf * 16 + quad * 4 + reg;
                const size_t off = (size_t)row * 512 + colg;
                const float s = rsc[rf][reg];
                const float ig = (float)acc[rf][cc][0][reg] * s + bsum[cc][0];
                const float fg = (float)acc[rf][cc][1][reg] * s + bsum[cc][1];
                const float gg = (float)acc[rf][cc][2][reg] * s + bsum[cc][2];
                const float og = (float)acc[rf][cc][3][reg] * s + bsum[cc][3];
                const float cp = __builtin_nontemporal_load(c_prev + off);
                const float cn = sigmoidf_(fg) * cp + sigmoidf_(ig) * tanhf_(gg);
                const float hn = sigmoidf_(og) * tanhf_(cn);
                __builtin_nontemporal_store(hn, h_out + off);
                __builtin_nontemporal_store(cn, c_out + off);
            }
        }
}

// ---- Fallback (round-1 kernel, proven): used only if ws_size < WS_NEEDED ----
#define LDSK 72
__device__ __forceinline__ u16 f2bf(float f) {
    u32 u = __builtin_bit_cast(u32, f);
    u += 0x7FFFu + ((u >> 16) & 1u);
    return (u16)(u >> 16);
}
__global__ __launch_bounds__(256, 3) void lstm_fused_v1(
    const float* __restrict__ x, const float* __restrict__ h_prev,
    const float* __restrict__ c_prev, const float* __restrict__ w_ih,
    const float* __restrict__ w_hh, const float* __restrict__ b_ih,
    const float* __restrict__ b_hh, float* __restrict__ h_out,
    float* __restrict__ c_out)
{
    __shared__ u16 sA[128][LDSK];
    __shared__ u16 sW[128][LDSK];
    const int t = threadIdx.x;
    const int bn = blockIdx.x & 15, bm = blockIdx.x >> 4;
    const int n0 = bn * 32, rowBase = bm * 128;
    const int srow = t >> 4, scol = t & 15;
    const int lane = t & 63, wv = t >> 6, colin = lane & 15, quad = lane >> 4;
    f32x4 acc[2][2][4];
    #pragma unroll
    for (int rf = 0; rf < 2; ++rf)
        #pragma unroll
        for (int cc = 0; cc < 2; ++cc)
            #pragma unroll
            for (int g = 0; g < 4; ++g) acc[rf][cc][g] = (f32x4){0.f, 0.f, 0.f, 0.f};
    for (int k0 = 0; k0 < KTOT; k0 += 64) {
        const int kk = (k0 < 512) ? k0 : (k0 - 512);
        const float* aSrc = (k0 < 512) ? x : h_prev;
        const float* wSrc = (k0 < 512) ? w_ih : w_hh;
        __syncthreads();
        #pragma unroll
        for (int p = 0; p < 8; ++p) {
            const int r = srow + p * 16;
            const float4 av = *(const float4*)(aSrc + (size_t)(rowBase + r) * 512 + kk + scol * 4);
            ushort4 ap; ap.x = f2bf(av.x); ap.y = f2bf(av.y); ap.z = f2bf(av.z); ap.w = f2bf(av.w);
            *(ushort4*)&sA[r][scol * 4] = ap;
            const int gate = r >> 5, rr = r & 31;
            const float4 wvv = *(const float4*)(wSrc + (size_t)(gate * 512 + n0 + rr) * 512 + kk + scol * 4);
            ushort4 wp; wp.x = f2bf(wvv.x); wp.y = f2bf(wvv.y); wp.z = f2bf(wvv.z); wp.w = f2bf(wvv.w);
            *(ushort4*)&sW[r][scol * 4] = wp;
        }
        __syncthreads();
        #pragma unroll
        for (int ks = 0; ks < 2; ++ks) {
            short8 af[2];
            #pragma unroll
            for (int rf = 0; rf < 2; ++rf)
                af[rf] = *(const short8*)&sA[wv * 32 + rf * 16 + colin][ks * 32 + quad * 8];
            short8 bfr[2][4];
            #pragma unroll
            for (int cc = 0; cc < 2; ++cc)
                #pragma unroll
                for (int g = 0; g < 4; ++g)
                    bfr[cc][g] = *(const short8*)&sW[g * 32 + cc * 16 + colin][ks * 32 + quad * 8];
            #pragma unroll
            for (int rf = 0; rf < 2; ++rf)
                #pragma unroll
                for (int cc = 0; cc < 2; ++cc)
                    #pragma unroll
                    for (int g = 0; g < 4; ++g)
                        acc[rf][cc][g] = __builtin_amdgcn_mfma_f32_16x16x32_bf16(
                            af[rf], bfr[cc][g], acc[rf][cc][g], 0, 0, 0);
        }
    }
    float bsum[2][4];
    #pragma unroll
    for (int cc = 0; cc < 2; ++cc) {
        const int colg = n0 + cc * 16 + colin;
        #pragma unroll
        for (int g = 0; g < 4; ++g) bsum[cc][g] = b_ih[g * 512 + colg] + b_hh[g * 512 + colg];
    }
    #pragma unroll
    for (int rf = 0; rf < 2; ++rf)
        #pragma unroll
        for (int cc = 0; cc < 2; ++cc) {
            const int colg = n0 + cc * 16 + colin;
            #pragma unroll
            for (int reg = 0; reg < 4; ++reg) {
                const int row = rowBase + wv * 32 + rf * 16 + quad * 4 + reg;
                const size_t off = (size_t)row * 512 + colg;
                const float ig = acc[rf][cc][0][reg] + bsum[cc][0];
                const float fg = acc[rf][cc][1][reg] + bsum[cc][1];
                const float gg = acc[rf][cc][2][reg] + bsum[cc][2];
                const float og = acc[rf][cc][3][reg] + bsum[cc][3];
                const float cp = c_prev[off];
                const float cn = sigmoidf_(fg) * cp + sigmoidf_(ig) * tanhf_(gg);
                const float hn = sigmoidf_(og) * tanhf_(cn);
                h_out[off] = hn;
                c_out[off] = cn;
            }
        }
}

extern "C" void kernel_launch(void* const* d_in, const int* in_sizes, int n_in,
                              void* d_out, int out_size, void* d_ws, size_t ws_size,
                              hipStream_t stream) {
    const float* x      = (const float*)d_in[0];
    const float* h_prev = (const float*)d_in[1];
    const float* c_prev = (const float*)d_in[2];
    const float* w_ih   = (const float*)d_in[3];
    const float* w_hh   = (const float*)d_in[4];
    const float* b_ih   = (const float*)d_in[5];
    const float* b_hh   = (const float*)d_in[6];
    float* h_out = (float*)d_out;
    float* c_out = h_out + (size_t)BATCH * HID;

    if (ws_size >= WS_NEEDED) {
        u8* wsA = (u8*)d_ws;
        u8* wsW = (u8*)d_ws + WSA_BYTES;
        float* aScale = (float*)((char*)d_ws + SCALE_OFF);
        float* part   = (float*)((char*)d_ws + PART_OFF);
        float* swOut  = (float*)((char*)d_ws + SW_OFF);
        pack_a_wmax<<<PACKA_BLOCKS + 512, 256, 0, stream>>>(x, h_prev, w_ih, w_hh,
                                                            wsA, aScale, part);
        pack_w<<<512, 256, 0, stream>>>(w_ih, w_hh, part, wsW, swOut);
        lstm_gemm<<<NBM * NBN, 256, 0, stream>>>(wsA, wsW, aScale, swOut, c_prev,
                                                 b_ih, b_hh, h_out, c_out);
    } else {
        lstm_fused_v1<<<128 * 16, 256, 0, stream>>>(x, h_prev, c_prev, w_ih, w_hh,
                                                    b_ih, b_hh, h_out, c_out);
    }
}